// Round 10
// baseline (46.372 us; speedup 1.0000x reference)
//
#include <hip/hip_runtime.h>
#include <math.h>

#define G      26
#define NA     5
#define NC     20
#define NB     128
#define NT     1024
#define GG     (G*G)            // 676
#define CELLS  (NB*NA*GG)       // 432640
#define CH     (NC+5)           // 25
#define WIN    256              // cells per wave-window
#define NWIN   (CELLS/WIN)      // 1690 (exact)
#define IGNORE_THRESH 0.6f
#define OBJ_SCALE   5.0f
#define NOOBJ_SCALE 1.0f
#define CLS_SCALE   1.0f
#define COORD_SCALE 1.0f
#define STRIDE_F    32.0f

typedef float f32x4 __attribute__((ext_vector_type(4)));

__device__ __constant__ float c_aw[NA] = {1.08f, 3.42f, 6.63f, 9.42f, 16.62f};
__device__ __constant__ float c_ah[NA] = {1.19f, 4.41f, 11.38f, 5.11f, 10.52f};

__device__ __forceinline__ float sigmoidf(float v) {
    return 1.0f / (1.0f + expf(-v));
}

// -------- Pass 0: fill cell_stat with -1 (separate dispatch: no races) --------
__global__ void k_init(int4* __restrict__ cell_stat4) {
    int i = blockIdx.x * 256 + threadIdx.x;
    if (i < CELLS / 4) cell_stat4[i] = make_int4(-1, -1, -1, -1);
}

// -------- Pass 1: target resolution -> sparse cell_stat scatter --------
__launch_bounds__(256)
__global__ void k_resolve(const float* __restrict__ tg,
                          int* __restrict__ cell_stat) {
    __shared__ int packed[NT];
    int tid = threadIdx.x;

    #pragma unroll
    for (int q = 0; q < 4; ++q) {
        int t = tid + q * 256;
        int   b  = (int)tg[t * 6 + 0];
        float cx = tg[t * 6 + 2] * (float)G;
        float cy = tg[t * 6 + 3] * (float)G;
        float gw = tg[t * 6 + 4] * (float)G;
        float gh = tg[t * 6 + 5] * (float)G;
        int gi = (int)floorf(cx);
        int gj = (int)floorf(cy);
        float best = -1.0f;
        int bn = 0, bits = 0;
        #pragma unroll
        for (int a = 0; a < NA; ++a) {
            float inter = fminf(c_aw[a], gw) * fminf(c_ah[a], gh);
            float uni   = c_aw[a] * c_ah[a] + 1e-16f + gw * gh - inter;
            float iou   = inter / uni;
            if (iou > best) { best = iou; bn = a; }      // first max wins (jnp.argmax)
            if (iou > IGNORE_THRESH) bits |= (1 << a);
        }
        int key = (b * G + gj) * G + gi;                 // < 86528, fits 17 bits
        packed[t] = (key << 8) | (bn << 5) | bits;
    }
    __syncthreads();

    int t    = blockIdx.x * 4 + (tid >> 6);              // wave -> target
    int lane = tid & 63;
    int me     = packed[t];
    int mykey  = me >> 8;
    int mybn   = (me >> 5) & 7;
    int mybits = me & 31;

    // agg: bits0-4 used anchors, bits5-9 earlier supp bits, bit10 not-winner
    int agg = 0;
    #pragma unroll
    for (int s = 0; s < 16; ++s) {
        int o  = lane + s * 64;
        int pv = packed[o];
        if ((pv >> 8) == mykey) {
            int obn = (pv >> 5) & 7;
            agg |= (1 << obn);                           // used
            if (o > t && obn == mybn) agg |= (1 << 10);  // later target owns cell
            if (o < t) agg |= (pv & 31) << 5;            // earlier supp rep
        }
    }
    #pragma unroll
    for (int off = 32; off > 0; off >>= 1) agg |= __shfl_xor(agg, off);

    if (lane == 0) {
        int used    = agg & 31;
        int earlier = (agg >> 5) & 31;
        bool winner = !(agg & (1 << 10));
        int cell0 = (mykey / GG) * (NA * GG) + (mykey % GG);
        if (winner) cell_stat[cell0 + mybn * GG] = t;
        #pragma unroll
        for (int a = 0; a < NA; ++a) {
            if ((mybits >> a & 1) && !(earlier >> a & 1) && !(used >> a & 1))
                cell_stat[cell0 + a * GG] = -2;          // suppressed, not obj
        }
    }
}

// -------- Pass 2: wave-per-window streaming (no barriers, no atomics) --------
// 64-thread block = 1 wave owns 256 cells: 25 f32x4 loads (1 KB/instr, 25.6 KB
// MLP), transform, transpose through wave-private 25.6 KB LDS, 25 coalesced
// 1 KB nontemporal store instrs. Loss partials -> private slot.
__launch_bounds__(64)
__global__ void k_main(const float* __restrict__ x,
                       const float* __restrict__ tg,
                       const int* __restrict__ cell_stat,
                       float* __restrict__ out,
                       float* __restrict__ partial) {
    __shared__ float stage[WIN * CH];        // 25600 B, single wave

    int t    = threadIdx.x;                  // 0..63
    int win  = blockIdx.x;                   // 0..NWIN-1
    int base = win * WIN;
    int c0   = base + t * 4;                 // quad base, %4 == 0
    int pa = c0 / GG;
    int sp = c0 % GG;                        // %4==0, <=672: quad stays in panel
    int an = pa % NA;
    float aw = c_aw[an], ah = c_ah[an];
    int i0 = sp % G, j0 = sp / G;

    // 25 wide loads issued up-front (independent -> all in flight)
    const float* xp = x + (size_t)pa * (CH * GG) + sp;
    f32x4 v[CH];
    #pragma unroll
    for (int c = 0; c < CH; ++c) v[c] = *(const f32x4*)(xp + c * GG);

    int4 ms4 = *(const int4*)(cell_stat + c0);   // quad status

    // transform + transpose-scatter into LDS [cell][ch]
    float pcf[4];
    #pragma unroll
    for (int c = 0; c < CH; ++c) {
        #pragma unroll
        for (int e = 0; e < 4; ++e) {
            float raw = v[c][e];
            int ie = i0 + e;
            int je = j0 + (ie >= G ? 1 : 0);
            ie -= (ie >= G ? G : 0);
            float val;
            if      (c == 0) val = (sigmoidf(raw) + (float)ie) * STRIDE_F;
            else if (c == 1) val = (sigmoidf(raw) + (float)je) * STRIDE_F;
            else if (c == 2) val = expf(raw) * aw * STRIDE_F;
            else if (c == 3) val = expf(raw) * ah * STRIDE_F;
            else             val = sigmoidf(raw);
            if (c == 4) pcf[e] = val;
            stage[(t * 4 + e) * CH + c] = val;
        }
    }

    // per-cell loss: {sx, sy, sw, sh, conf_obj, conf_noobj, cls, n_obj, n_noobj}
    float p[9];
    #pragma unroll
    for (int q = 0; q < 9; ++q) p[q] = 0.0f;

    const int* msp = (const int*)&ms4;
    #pragma unroll
    for (int e = 0; e < 4; ++e) {
        int m = msp[e];
        if (m == -1) {                           // plain noobj cell
            p[5] += pcf[e] * pcf[e];             // tconf == 0 here
            p[8] += 1.0f;
        } else if (m >= 0) {                     // obj cell, target m
            int ie = i0 + e;
            int je = j0 + (ie >= G ? 1 : 0);
            ie -= (ie >= G ? G : 0);
            float px = sigmoidf(v[0][e]);
            float py = sigmoidf(v[1][e]);
            float pw = v[2][e], ph = v[3][e];
            float pconf = pcf[e];
            float bx = px + (float)ie;
            float by = py + (float)je;
            float bw = expf(pw) * aw;
            float bh = expf(ph) * ah;

            float cx = tg[m * 6 + 2] * (float)G;
            float cy = tg[m * 6 + 3] * (float)G;
            float gw2 = tg[m * 6 + 4] * (float)G;
            float gh2 = tg[m * 6 + 5] * (float)G;
            int label = (int)tg[m * 6 + 1];
            float tx = cx - floorf(cx);
            float ty = cy - floorf(cy);
            float tw = logf(gw2 / aw + 1e-16f);
            float th = logf(gh2 / ah + 1e-16f);

            float b1x1 = bx - bw * 0.5f, b1x2 = bx + bw * 0.5f;
            float b1y1 = by - bh * 0.5f, b1y2 = by + bh * 0.5f;
            float b2x1 = cx - gw2 * 0.5f, b2x2 = cx + gw2 * 0.5f;
            float b2y1 = cy - gh2 * 0.5f, b2y2 = cy + gh2 * 0.5f;
            float iw = fmaxf(fminf(b1x2, b2x2) - fmaxf(b1x1, b2x1) + 1.0f, 0.0f);
            float ih = fmaxf(fminf(b1y2, b2y2) - fmaxf(b1y1, b2y1) + 1.0f, 0.0f);
            float inter = iw * ih;
            float a1 = (b1x2 - b1x1 + 1.0f) * (b1y2 - b1y1 + 1.0f);
            float a2 = (b2x2 - b2x1 + 1.0f) * (b2y2 - b2y1 + 1.0f);
            float iou = inter / (a1 + a2 - inter + 1e-16f);

            p[0] += (px - tx) * (px - tx);
            p[1] += (py - ty) * (py - ty);
            p[2] += (pw - tw) * (pw - tw);
            p[3] += (ph - th) * (ph - th);
            p[4] += (pconf - iou) * (pconf - iou);
            float cls = 0.0f;
            #pragma unroll
            for (int c = 0; c < NC; ++c) {
                float pcv = fminf(fmaxf(sigmoidf(v[5 + c][e]), 1e-12f), 1.0f - 1e-12f);
                float tc = (c == label) ? 1.0f : 0.0f;
                cls -= tc * logf(pcv) + (1.0f - tc) * logf(1.0f - pcv);
            }
            p[6] += cls;
            p[7] += 1.0f;
        }                                        // m == -2: suppressed, skip
    }

    // transpose-read + nontemporal coalesced store (1600 f4 per window)
    const f32x4* st = (const f32x4*)stage;
    f32x4* ob = (f32x4*)(out + (size_t)base * CH);
    #pragma unroll
    for (int r = 0; r < 25; ++r)
        __builtin_nontemporal_store(st[r * 64 + t], &ob[r * 64 + t]);

    // wave shuffle-reduce -> private slot (plain stores, no atomics)
    #pragma unroll
    for (int o = 32; o > 0; o >>= 1) {
        #pragma unroll
        for (int q = 0; q < 9; ++q) p[q] += __shfl_down(p[q], o);
    }
    if (t == 0) {
        float* ps = partial + (size_t)win * 16;
        #pragma unroll
        for (int q = 0; q < 9; ++q) ps[q] = p[q];
    }
}

// -------- Pass 3: reduce per-window partials + finalize --------
__launch_bounds__(1024)
__global__ void k_final(const float* __restrict__ partial,
                        float* __restrict__ loss_out) {
    __shared__ float red[16][9];
    int t = threadIdx.x;

    f32x4 A = {0, 0, 0, 0}, B = {0, 0, 0, 0};
    float C = 0.0f;
    for (int sIdx = t; sIdx < NWIN; sIdx += 1024) {
        const f32x4* q4 = (const f32x4*)(partial + (size_t)sIdx * 16);
        A += q4[0];
        B += q4[1];
        C += partial[(size_t)sIdx * 16 + 8];
    }
    float p[9] = {A.x, A.y, A.z, A.w, B.x, B.y, B.z, B.w, C};

    #pragma unroll
    for (int o = 32; o > 0; o >>= 1) {
        #pragma unroll
        for (int q = 0; q < 9; ++q) p[q] += __shfl_down(p[q], o);
    }
    int lane = t & 63, wid = t >> 6;
    if (lane == 0) {
        #pragma unroll
        for (int q = 0; q < 9; ++q) red[wid][q] = p[q];
    }
    __syncthreads();

    if (t == 0) {
        float sv[9];
        #pragma unroll
        for (int q = 0; q < 9; ++q) {
            float acc_q = 0.0f;
            for (int ww = 0; ww < 16; ++ww) acc_q += red[ww][q];
            sv[q] = acc_q;
        }
        float n_obj   = sv[7];
        float n_noobj = sv[8];
        float l = COORD_SCALE * (sv[0] + sv[1] + sv[2] + sv[3]) / n_obj
                + OBJ_SCALE * sv[4] / n_obj
                + NOOBJ_SCALE * sv[5] / n_noobj
                + CLS_SCALE * sv[6] / (n_obj * (float)NC);
        *loss_out = l;
    }
}

extern "C" void kernel_launch(void* const* d_in, const int* in_sizes, int n_in,
                              void* d_out, int out_size, void* d_ws, size_t ws_size,
                              hipStream_t stream) {
    const float* x  = (const float*)d_in[0];
    const float* tg = (const float*)d_in[1];
    float* out = (float*)d_out;

    char* ws = (char*)d_ws;
    int*   cell_stat = (int*)ws;                          // CELLS ints (1.73 MB)
    float* partial   = (float*)(ws + (size_t)CELLS * 4);  // NWIN*16 floats (108 KB)

    k_init<<<(CELLS / 4 + 255) / 256, 256, 0, stream>>>((int4*)cell_stat);
    k_resolve<<<NT / 4, 256, 0, stream>>>(tg, cell_stat);
    k_main<<<NWIN, 64, 0, stream>>>(x, tg, cell_stat, out, partial);
    k_final<<<1, 1024, 0, stream>>>(partial, out + (size_t)CELLS * CH);
}

// Round 11
// 41.175 us; speedup vs baseline: 1.1262x; 1.1262x over previous
//
#include <hip/hip_runtime.h>
#include <math.h>

#define G      26
#define NA     5
#define NC     20
#define NB     128
#define NT     1024
#define GG     (G*G)            // 676
#define CELLS  (NB*NA*GG)       // 432640
#define CH     (NC+5)           // 25
#define NWAVE  (CELLS/64)       // 6760 (exact)
#define NBLK   (NWAVE/4)        // 1690
#define IGNORE_THRESH 0.6f
#define OBJ_SCALE   5.0f
#define NOOBJ_SCALE 1.0f
#define CLS_SCALE   1.0f
#define COORD_SCALE 1.0f
#define STRIDE_F    32.0f

typedef float f32x4 __attribute__((ext_vector_type(4)));

__device__ __constant__ float c_aw[NA] = {1.08f, 3.42f, 6.63f, 9.42f, 16.62f};
__device__ __constant__ float c_ah[NA] = {1.19f, 4.41f, 11.38f, 5.11f, 10.52f};

__device__ __forceinline__ float sigmoidf(float v) {
    return 1.0f / (1.0f + expf(-v));
}

// -------- Pass 0: fill cell_stat with -1 (separate dispatch: no races) --------
__global__ void k_init(int4* __restrict__ cell_stat4) {
    int i = blockIdx.x * 256 + threadIdx.x;
    if (i < CELLS / 4) cell_stat4[i] = make_int4(-1, -1, -1, -1);
}

// -------- Pass 1: target resolution -> sparse cell_stat scatter --------
__launch_bounds__(256)
__global__ void k_resolve(const float* __restrict__ tg,
                          int* __restrict__ cell_stat) {
    __shared__ int packed[NT];
    int tid = threadIdx.x;

    #pragma unroll
    for (int q = 0; q < 4; ++q) {
        int t = tid + q * 256;
        int   b  = (int)tg[t * 6 + 0];
        float cx = tg[t * 6 + 2] * (float)G;
        float cy = tg[t * 6 + 3] * (float)G;
        float gw = tg[t * 6 + 4] * (float)G;
        float gh = tg[t * 6 + 5] * (float)G;
        int gi = (int)floorf(cx);
        int gj = (int)floorf(cy);
        float best = -1.0f;
        int bn = 0, bits = 0;
        #pragma unroll
        for (int a = 0; a < NA; ++a) {
            float inter = fminf(c_aw[a], gw) * fminf(c_ah[a], gh);
            float uni   = c_aw[a] * c_ah[a] + 1e-16f + gw * gh - inter;
            float iou   = inter / uni;
            if (iou > best) { best = iou; bn = a; }      // first max wins (jnp.argmax)
            if (iou > IGNORE_THRESH) bits |= (1 << a);
        }
        int key = (b * G + gj) * G + gi;                 // < 86528, fits 17 bits
        packed[t] = (key << 8) | (bn << 5) | bits;
    }
    __syncthreads();

    int t    = blockIdx.x * 4 + (tid >> 6);              // wave -> target
    int lane = tid & 63;
    int me     = packed[t];
    int mykey  = me >> 8;
    int mybn   = (me >> 5) & 7;
    int mybits = me & 31;

    // agg: bits0-4 used anchors, bits5-9 earlier supp bits, bit10 not-winner
    int agg = 0;
    #pragma unroll
    for (int s = 0; s < 16; ++s) {
        int o  = lane + s * 64;
        int pv = packed[o];
        if ((pv >> 8) == mykey) {
            int obn = (pv >> 5) & 7;
            agg |= (1 << obn);                           // used
            if (o > t && obn == mybn) agg |= (1 << 10);  // later target owns cell
            if (o < t) agg |= (pv & 31) << 5;            // earlier supp rep
        }
    }
    #pragma unroll
    for (int off = 32; off > 0; off >>= 1) agg |= __shfl_xor(agg, off);

    if (lane == 0) {
        int used    = agg & 31;
        int earlier = (agg >> 5) & 31;
        bool winner = !(agg & (1 << 10));
        int cell0 = (mykey / GG) * (NA * GG) + (mykey % GG);
        if (winner) cell_stat[cell0 + mybn * GG] = t;
        #pragma unroll
        for (int a = 0; a < NA; ++a) {
            if ((mybits >> a & 1) && !(earlier >> a & 1) && !(used >> a & 1))
                cell_stat[cell0 + a * GG] = -2;          // suppressed, not obj
        }
    }
}

// -------- Pass 2: wave-autonomous streaming (NO barriers, NO atomics) --------
// R9 structure + bijective XCD-chunked block swizzle (m204 variant): each XCD
// gets a CONTIGUOUS range of windows -> sequential HBM/channel streams per
// XCD L2 instead of 8-way interleaved hops.
__launch_bounds__(256)
__global__ void k_main(const float* __restrict__ x,
                       const float* __restrict__ tg,
                       const int* __restrict__ cell_stat,
                       float* __restrict__ out,
                       float* __restrict__ partial) {
    __shared__ float stageAll[4][64 * CH];   // 25600 B

    // bijective XCD-chunk swizzle: NBLK = 1690 = 8*211 + 2
    const int q = NBLK / 8, r = NBLK % 8;
    int xcd = blockIdx.x & 7;
    int pos = blockIdx.x >> 3;
    int blk = (xcd < r) ? xcd * (q + 1) + pos
                        : r * (q + 1) + (xcd - r) * q + pos;

    int tid  = threadIdx.x;
    int lane = tid & 63;
    int w    = tid >> 6;
    int gw   = blk * 4 + w;                  // global wave id, 0..NWAVE-1
    int cell = gw * 64 + lane;

    int m  = cell_stat[cell];                // -1 plain / -2 supp / >=0 obj tgt
    int pa = cell / GG;                      // b*NA + a
    int sp = cell % GG;
    int an = pa % NA;
    float aw = c_aw[an], ah = c_ah[an];
    int i = sp % G, j = sp / G;

    const float* xp = x + (size_t)pa * (CH * GG) + sp;
    float v[CH];
    #pragma unroll
    for (int c = 0; c < CH; ++c) v[c] = xp[(size_t)c * GG];

    float px = sigmoidf(v[0]);
    float py = sigmoidf(v[1]);
    float pconf = sigmoidf(v[4]);
    float bx = px + (float)i;
    float by = py + (float)j;
    float bw = expf(v[2]) * aw;
    float bh = expf(v[3]) * ah;

    float* s = &stageAll[w][lane * CH];      // stride 25 (odd): 2-way, free
    s[0] = bx * STRIDE_F;
    s[1] = by * STRIDE_F;
    s[2] = bw * STRIDE_F;
    s[3] = bh * STRIDE_F;
    s[4] = pconf;
    #pragma unroll
    for (int c = 0; c < NC; ++c) s[5 + c] = sigmoidf(v[5 + c]);

    // wave-local transpose read + nontemporal store (400 f4 per wave)
    const f32x4* st = (const f32x4*)stageAll[w];
    f32x4* ob = (f32x4*)(out + (size_t)gw * (64 * CH));
    #pragma unroll
    for (int rr = 0; rr < 6; ++rr)
        __builtin_nontemporal_store(st[rr * 64 + lane], &ob[rr * 64 + lane]);
    if (lane < 16)
        __builtin_nontemporal_store(st[384 + lane], &ob[384 + lane]);

    // per-cell loss: {sx, sy, sw, sh, conf_obj, conf_noobj, cls, n_obj, n_noobj}
    float p[9];
    #pragma unroll
    for (int qq = 0; qq < 9; ++qq) p[qq] = 0.0f;

    if (m == -1) {                           // plain noobj cell
        p[5] = pconf * pconf;                // tconf == 0 here
        p[8] = 1.0f;
    } else if (m >= 0) {                     // obj cell, target m
        float cx = tg[m * 6 + 2] * (float)G;
        float cy = tg[m * 6 + 3] * (float)G;
        float gw2 = tg[m * 6 + 4] * (float)G;
        float gh2 = tg[m * 6 + 5] * (float)G;
        int label = (int)tg[m * 6 + 1];
        float tx = cx - floorf(cx);
        float ty = cy - floorf(cy);
        float tw = logf(gw2 / aw + 1e-16f);
        float th = logf(gh2 / ah + 1e-16f);

        float b1x1 = bx - bw * 0.5f, b1x2 = bx + bw * 0.5f;
        float b1y1 = by - bh * 0.5f, b1y2 = by + bh * 0.5f;
        float b2x1 = cx - gw2 * 0.5f, b2x2 = cx + gw2 * 0.5f;
        float b2y1 = cy - gh2 * 0.5f, b2y2 = cy + gh2 * 0.5f;
        float iw = fmaxf(fminf(b1x2, b2x2) - fmaxf(b1x1, b2x1) + 1.0f, 0.0f);
        float ih = fmaxf(fminf(b1y2, b2y2) - fmaxf(b1y1, b2y1) + 1.0f, 0.0f);
        float inter = iw * ih;
        float a1 = (b1x2 - b1x1 + 1.0f) * (b1y2 - b1y1 + 1.0f);
        float a2 = (b2x2 - b2x1 + 1.0f) * (b2y2 - b2y1 + 1.0f);
        float iou = inter / (a1 + a2 - inter + 1e-16f);

        p[0] = (px - tx) * (px - tx);
        p[1] = (py - ty) * (py - ty);
        p[2] = (v[2] - tw) * (v[2] - tw);
        p[3] = (v[3] - th) * (v[3] - th);
        p[4] = (pconf - iou) * (pconf - iou);
        float cls = 0.0f;
        #pragma unroll
        for (int c = 0; c < NC; ++c) {
            float pcv = fminf(fmaxf(s[5 + c], 1e-12f), 1.0f - 1e-12f);
            float tc = (c == label) ? 1.0f : 0.0f;
            cls -= tc * logf(pcv) + (1.0f - tc) * logf(1.0f - pcv);
        }
        p[6] = cls;
        p[7] = 1.0f;
    }                                        // m == -2: suppressed, skip

    #pragma unroll
    for (int o = 32; o > 0; o >>= 1) {
        #pragma unroll
        for (int qq = 0; qq < 9; ++qq) p[qq] += __shfl_down(p[qq], o);
    }
    if (lane == 0) {                         // private slot: plain stores
        float* ps = partial + (size_t)gw * 16;
        #pragma unroll
        for (int qq = 0; qq < 9; ++qq) ps[qq] = p[qq];
    }
}

// -------- Pass 3: reduce per-wave partials + finalize --------
__launch_bounds__(1024)
__global__ void k_final(const float* __restrict__ partial,
                        float* __restrict__ loss_out) {
    __shared__ float red[16][9];
    int t = threadIdx.x;

    f32x4 A = {0, 0, 0, 0}, B = {0, 0, 0, 0};
    float C = 0.0f;
    for (int sIdx = t; sIdx < NWAVE; sIdx += 1024) {
        const f32x4* q4 = (const f32x4*)(partial + (size_t)sIdx * 16);
        A += q4[0];
        B += q4[1];
        C += partial[(size_t)sIdx * 16 + 8];
    }
    float p[9] = {A.x, A.y, A.z, A.w, B.x, B.y, B.z, B.w, C};

    #pragma unroll
    for (int o = 32; o > 0; o >>= 1) {
        #pragma unroll
        for (int q = 0; q < 9; ++q) p[q] += __shfl_down(p[q], o);
    }
    int lane = t & 63, wid = t >> 6;
    if (lane == 0) {
        #pragma unroll
        for (int q = 0; q < 9; ++q) red[wid][q] = p[q];
    }
    __syncthreads();

    if (t == 0) {
        float sv[9];
        #pragma unroll
        for (int q = 0; q < 9; ++q) {
            float acc_q = 0.0f;
            for (int ww = 0; ww < 16; ++ww) acc_q += red[ww][q];
            sv[q] = acc_q;
        }
        float n_obj   = sv[7];
        float n_noobj = sv[8];
        float l = COORD_SCALE * (sv[0] + sv[1] + sv[2] + sv[3]) / n_obj
                + OBJ_SCALE * sv[4] / n_obj
                + NOOBJ_SCALE * sv[5] / n_noobj
                + CLS_SCALE * sv[6] / (n_obj * (float)NC);
        *loss_out = l;
    }
}

extern "C" void kernel_launch(void* const* d_in, const int* in_sizes, int n_in,
                              void* d_out, int out_size, void* d_ws, size_t ws_size,
                              hipStream_t stream) {
    const float* x  = (const float*)d_in[0];
    const float* tg = (const float*)d_in[1];
    float* out = (float*)d_out;

    char* ws = (char*)d_ws;
    int*   cell_stat = (int*)ws;                          // CELLS ints (1.73 MB)
    float* partial   = (float*)(ws + (size_t)CELLS * 4);  // NWAVE*16 floats (433 KB)

    k_init<<<(CELLS / 4 + 255) / 256, 256, 0, stream>>>((int4*)cell_stat);
    k_resolve<<<NT / 4, 256, 0, stream>>>(tg, cell_stat);
    k_main<<<NBLK, 256, 0, stream>>>(x, tg, cell_stat, out, partial);
    k_final<<<1, 1024, 0, stream>>>(partial, out + (size_t)CELLS * CH);
}